// Round 1
// baseline (377.317 us; speedup 1.0000x reference)
//
#include <hip/hip_runtime.h>

typedef _Float16 f16;
typedef f16 f16x2 __attribute__((ext_vector_type(2)));
typedef f16 f16x4 __attribute__((ext_vector_type(4)));
typedef f16 f16x8 __attribute__((ext_vector_type(8)));
typedef float f32x4 __attribute__((ext_vector_type(4)));

#define MFMA16(a, b, c) __builtin_amdgcn_mfma_f32_16x16x32_f16((a), (b), (c), 0, 0, 0)

__device__ __forceinline__ f16x8 cat8(f16x4 a, f16x4 b) {
    return __builtin_shufflevector(a, b, 0, 1, 2, 3, 4, 5, 6, 7);
}
__device__ __forceinline__ f16x4 lo4(f16x8 v) { return __builtin_shufflevector(v, v, 0, 1, 2, 3); }
__device__ __forceinline__ f16x4 hi4(f16x8 v) { return __builtin_shufflevector(v, v, 4, 5, 6, 7); }

// ---------------- LDS layout for the fused attention kernel (bytes) ----------------
#define LDA_XA 132                    // f16 [256][132]  X[t][c]    (reused as agg[t][c])
#define OFF_XA 0
#define LDA_T  72                     // f16 [256][72]   T[n][m] / Y[k][m]
#define OFF_T  67584
#define OFF_Y  (67584 + 36864)
#define LDA_XB 264                    // f16 [128][264]  X^T[c][t]  (overlaps T/Y region)
#define OFF_XB 67584
#define LDA_PS 36                     // per-wave f16 [32][36] P staging
#define OFF_PS (67584 + 73728)
#define OFF_SST (OFF_PS + 8 * 32 * LDA_PS * 2)
#define LDS_ATT (OFF_SST + 256 * 4)   // = 160768 <= 163840

// =====================================================================================
// repack: x fp32 [B,C,H,W] -> Xall f16 [b][n2=(i2,j2)][n1=(i1,j1)][c]
// one workgroup per (b, i1, i2) image row h = i1*16+i2
// =====================================================================================
__global__ __launch_bounds__(512) void repack_kernel(const float* __restrict__ x,
                                                     f16* __restrict__ Xall) {
    __shared__ f16 XT[128 * 264];     // [c][w], padded
    const int tid = threadIdx.x, g = blockIdx.x;
    const int b = g >> 8, i1 = (g >> 4) & 15, i2 = g & 15;
    const int h = i1 * 16 + i2;
    {
        const int c = tid >> 2, wq = (tid & 3) * 64;
        const float* src = x + (((size_t)b * 128 + c) * 256 + h) * 256 + wq;
        f16* dst = XT + c * 264 + wq;
#pragma unroll
        for (int i = 0; i < 16; ++i) {
            f32x4 v = *(const f32x4*)(src + i * 4);
            f16x4 o = {(f16)v[0], (f16)v[1], (f16)v[2], (f16)v[3]};
            *(f16x4*)(dst + i * 4) = o;
        }
    }
    __syncthreads();
    {
        const int w = tid >> 1, ch = (tid & 1) * 64;   // w = j1*16 + j2
        const int j1 = w >> 4, j2 = w & 15;
        f16* dst = Xall + (((size_t)b * 256 + i2 * 16 + j2) * 256 + i1 * 16 + j1) * 128 + ch;
#pragma unroll
        for (int i = 0; i < 8; ++i) {
            f16x8 v;
#pragma unroll
            for (int j = 0; j < 8; ++j) v[j] = XT[(ch + i * 8 + j) * 264 + w];
            *(f16x8*)(dst + i * 8) = v;
        }
    }
}

// =====================================================================================
// weight conversion fp32 -> f16 (both passes)
// =====================================================================================
__global__ void wconv_kernel(const float* __restrict__ w1x, const float* __restrict__ w1y,
                             const float* __restrict__ w1o, const float* __restrict__ w2x,
                             const float* __restrict__ w2y, const float* __restrict__ w2o,
                             f16* __restrict__ Wbf) {
    int i = blockIdx.x * 256 + threadIdx.x;
    float v;
    if (i < 8192)       v = w1x[i];
    else if (i < 16384) v = w1y[i - 8192];
    else if (i < 32768) v = w1o[i - 16384];
    else if (i < 40960) v = w2x[i - 32768];
    else if (i < 49152) v = w2y[i - 40960];
    else                v = w2o[i - 49152];
    Wbf[i] = (f16)v;
}

// =====================================================================================
// fused per-block attention:
//   Xin f16 chunk [t][c] (g*32768) -> theta/psi -> S -> softmax -> PV -> Wo
//   writes pre-BN out f16 to Uout with strides (t_stride, s_stride); accumulates BN stats
// =====================================================================================
template <int PASS>
__global__ __launch_bounds__(512, 2) void att_kernel(
    const f16* __restrict__ Xin, const f16* __restrict__ Wq, const f16* __restrict__ Wk,
    const f16* __restrict__ Wo, const float* __restrict__ bq, const float* __restrict__ bk,
    const float* __restrict__ bo, const float* __restrict__ bnab, f16* __restrict__ Uout,
    float* __restrict__ gstats, int t_stride, int s_stride) {
    __shared__ __align__(16) char smem[LDS_ATT];
    f16* XA = (f16*)(smem + OFF_XA);
    f16* TL = (f16*)(smem + OFF_T);
    f16* YL = (f16*)(smem + OFF_Y);
    f16* XB = (f16*)(smem + OFF_XB);
    float* SST = (float*)(smem + OFF_SST);

    const int tid = threadIdx.x;
    const int w = tid >> 6, l = tid & 63, lq = l >> 4, lr = l & 15;
    const int g = blockIdx.x;
    const int R0 = w * 32;
    f16* PS = (f16*)(smem + OFF_PS) + w * (32 * LDA_PS);

    if (tid < 256) SST[tid] = 0.f;

    // ---- phase 0: load chunk -> XA[t][c] (pass2 applies BN1+ReLU) ----
    {
        const f16* src = Xin + (size_t)g * 32768;
        const int c0 = (tid & 15) * 8;
        float a[8], bsh[8];
        if constexpr (PASS == 2) {
#pragma unroll
            for (int j = 0; j < 8; ++j) { a[j] = bnab[c0 + j]; bsh[j] = bnab[128 + c0 + j]; }
        }
#pragma unroll
        for (int e = 0; e < 8; ++e) {
            int u = e * 4096 + tid * 8;
            int t2 = u >> 7;
            f16x8 v = *(const f16x8*)(src + u);
            if constexpr (PASS == 2) {
#pragma unroll
                for (int j = 0; j < 8; ++j) {
                    float f = fmaxf(a[j] * (float)v[j] + bsh[j], 0.f);
                    v[j] = (f16)f;
                }
            }
            f16* dst = XA + t2 * LDA_XA + c0;
            *(f16x4*)dst = lo4(v);
            *(f16x4*)(dst + 4) = hi4(v);
        }
    }
    __syncthreads();

    // ---- GEMM1: T[n,m] = X @ Wq^T + bq ; Y[k,m] = X @ Wk^T + bk ----
    {
        f32x4 accT[2][4] = {};
        f32x4 accY[2][4] = {};
#pragma unroll
        for (int ks = 0; ks < 4; ++ks) {
            f16x8 afr[2];
#pragma unroll
            for (int mt = 0; mt < 2; ++mt) {
                const f16* p = XA + (R0 + mt * 16 + lr) * LDA_XA + ks * 32 + lq * 8;
                afr[mt] = cat8(*(const f16x4*)p, *(const f16x4*)(p + 4));
            }
#pragma unroll
            for (int nt = 0; nt < 4; ++nt) {
                f16x8 bq8 = *(const f16x8*)(Wq + (nt * 16 + lr) * 128 + ks * 32 + lq * 8);
                f16x8 bk8 = *(const f16x8*)(Wk + (nt * 16 + lr) * 128 + ks * 32 + lq * 8);
#pragma unroll
                for (int mt = 0; mt < 2; ++mt) {
                    accT[mt][nt] = MFMA16(afr[mt], bq8, accT[mt][nt]);
                    accY[mt][nt] = MFMA16(afr[mt], bk8, accY[mt][nt]);
                }
            }
        }
#pragma unroll
        for (int nt = 0; nt < 4; ++nt) {
            float bqv = bq[nt * 16 + lr], bkv = bk[nt * 16 + lr];
#pragma unroll
            for (int mt = 0; mt < 2; ++mt)
#pragma unroll
                for (int r = 0; r < 4; ++r) {
                    int n = R0 + mt * 16 + lq * 4 + r;
                    TL[n * LDA_T + nt * 16 + lr] = (f16)(accT[mt][nt][r] + bqv);
                    YL[n * LDA_T + nt * 16 + lr] = (f16)(accY[mt][nt][r] + bkv);
                }
        }
    }
    __syncthreads();

    // ---- GEMM2: S[n,k] = T[n,:] . Y[k,:]  (each wave owns 32 rows of S) ----
    f32x4 s[2][16] = {};
    {
        f16x8 a2[2][2];
#pragma unroll
        for (int mt = 0; mt < 2; ++mt)
#pragma unroll
            for (int ks = 0; ks < 2; ++ks)
                a2[mt][ks] = *(const f16x8*)(TL + (R0 + mt * 16 + lr) * LDA_T + ks * 32 + lq * 8);
#pragma unroll
        for (int kt = 0; kt < 16; ++kt) {
#pragma unroll
            for (int ks = 0; ks < 2; ++ks) {
                f16x8 b2 = *(const f16x8*)(YL + (kt * 16 + lr) * LDA_T + ks * 32 + lq * 8);
#pragma unroll
                for (int mt = 0; mt < 2; ++mt) s[mt][kt] = MFMA16(a2[mt][ks], b2, s[mt][kt]);
            }
        }
    }

    // ---- softmax over k (rows n), wave-parallel ----
    float rscale[2][4];
#pragma unroll
    for (int mt = 0; mt < 2; ++mt)
#pragma unroll
        for (int r = 0; r < 4; ++r) {
            float m = -1e30f;
#pragma unroll
            for (int kt = 0; kt < 16; ++kt) m = fmaxf(m, s[mt][kt][r]);
#pragma unroll
            for (int off = 1; off < 16; off <<= 1) m = fmaxf(m, __shfl_xor(m, off));
            float sum = 0.f;
#pragma unroll
            for (int kt = 0; kt < 16; ++kt) {
                float p = __expf(s[mt][kt][r] - m);
                s[mt][kt][r] = p;
                sum += p;
            }
#pragma unroll
            for (int off = 1; off < 16; off <<= 1) sum += __shfl_xor(sum, off);
            rscale[mt][r] = 1.f / sum;
        }
    __syncthreads();   // all waves finished reading TL/YL

    // ---- build X^T[c][t] into XB (overwrites T/Y region) ----
    {
        const int c = tid & 127, tb = (tid >> 7) * 64;
#pragma unroll 4
        for (int i = 0; i < 32; ++i) {
            int t = tb + 2 * i;
            f16x2 pv;
            pv[0] = XA[t * LDA_XA + c];
            pv[1] = XA[(t + 1) * LDA_XA + c];
            *(f16x2*)(XB + c * LDA_XB + t) = pv;
        }
    }
    __syncthreads();

    // ---- GEMM5 (PV): agg[n,c] = P[n,:] @ X[:,c], P staged per-wave via LDS ----
    f32x4 g5[2][8] = {};
#pragma unroll
    for (int kc = 0; kc < 8; ++kc) {
#pragma unroll
        for (int mt = 0; mt < 2; ++mt)
#pragma unroll
            for (int d = 0; d < 2; ++d) {
                int kt = kc * 2 + d;
#pragma unroll
                for (int r = 0; r < 4; ++r) {
                    float p = s[mt][kt][r] * rscale[mt][r];
                    PS[(mt * 16 + lq * 4 + r) * LDA_PS + d * 16 + lr] = (f16)p;
                }
            }
        f16x8 ap[2];
#pragma unroll
        for (int mt = 0; mt < 2; ++mt) {
            const f16* p = PS + (mt * 16 + lr) * LDA_PS + lq * 8;
            ap[mt] = cat8(*(const f16x4*)p, *(const f16x4*)(p + 4));
        }
#pragma unroll
        for (int ct = 0; ct < 8; ++ct) {
            f16x8 bx8 = *(const f16x8*)(XB + (ct * 16 + lr) * LDA_XB + kc * 32 + lq * 8);
#pragma unroll
            for (int mt = 0; mt < 2; ++mt) g5[mt][ct] = MFMA16(ap[mt], bx8, g5[mt][ct]);
        }
    }

    // ---- stage agg (per-wave rows) into XA region; GEMM6: out = agg @ Wo^T + bo ----
    f16* AG = XA;
#pragma unroll
    for (int ct = 0; ct < 8; ++ct)
#pragma unroll
        for (int mt = 0; mt < 2; ++mt)
#pragma unroll
            for (int r = 0; r < 4; ++r)
                AG[(R0 + mt * 16 + lq * 4 + r) * LDA_XA + ct * 16 + lr] = (f16)g5[mt][ct][r];

    f32x4 o6[2][8] = {};
#pragma unroll
    for (int ks = 0; ks < 4; ++ks) {
        f16x8 a6[2];
#pragma unroll
        for (int mt = 0; mt < 2; ++mt) {
            const f16* p = AG + (R0 + mt * 16 + lr) * LDA_XA + ks * 32 + lq * 8;
            a6[mt] = cat8(*(const f16x4*)p, *(const f16x4*)(p + 4));
        }
#pragma unroll
        for (int ot = 0; ot < 8; ++ot) {
            f16x8 bw = *(const f16x8*)(Wo + (ot * 16 + lr) * 128 + ks * 32 + lq * 8);
#pragma unroll
            for (int mt = 0; mt < 2; ++mt) o6[mt][ot] = MFMA16(a6[mt], bw, o6[mt][ot]);
        }
    }

    // ---- epilogue: bias, BN-stat partials, store pre-BN f16 ----
    const size_t ub = (size_t)(g >> 8) * 8388608 + (size_t)(g & 255) * (size_t)s_stride;
#pragma unroll
    for (int ot = 0; ot < 8; ++ot) {
        float bov = bo[ot * 16 + lr];
        float ss = 0.f, sq = 0.f;
#pragma unroll
        for (int mt = 0; mt < 2; ++mt)
#pragma unroll
            for (int r = 0; r < 4; ++r) {
                float v = o6[mt][ot][r] + bov;
                ss += v;
                sq += v * v;
                int t = R0 + mt * 16 + lq * 4 + r;
                Uout[ub + (size_t)t * (size_t)t_stride + ot * 16 + lr] = (f16)v;
            }
        ss += __shfl_xor(ss, 16); ss += __shfl_xor(ss, 32);
        sq += __shfl_xor(sq, 16); sq += __shfl_xor(sq, 32);
        if (lq == 0) {
            atomicAdd(&SST[ot * 16 + lr], ss);
            atomicAdd(&SST[128 + ot * 16 + lr], sq);
        }
    }
    __syncthreads();
    if (tid < 256) atomicAdd(&gstats[tid], SST[tid]);
}

// =====================================================================================
// BN stats finalize: (sum, sumsq) -> (a, b) with y = a*x + b
// =====================================================================================
__global__ void bnfix_kernel(const float* __restrict__ gstats, const float* __restrict__ gamma,
                             const float* __restrict__ beta, float* __restrict__ ab) {
    int c = threadIdx.x;
    if (c < 128) {
        const float inv = 1.f / 262144.f;
        float mean = gstats[c] * inv;
        float var = gstats[128 + c] * inv - mean * mean;
        float rstd = rsqrtf(var + 1e-5f);
        float a = gamma[c] * rstd;
        ab[c] = a;
        ab[128 + c] = beta[c] - mean * a;
    }
}

// =====================================================================================
// final: U2 f16 [b][n1][n2][c] -> BN2+ReLU -> out fp32 [B,C,H,W]
// =====================================================================================
__global__ __launch_bounds__(256) void final_kernel(const f16* __restrict__ U2,
                                                    const float* __restrict__ ab,
                                                    float* __restrict__ out) {
    __shared__ f16 L[256 * 132];      // [n2][c] padded
    const int tid = threadIdx.x, g = blockIdx.x;
    const int b = g >> 8, i1 = (g >> 4) & 15, j1 = g & 15;
    const f16* src = U2 + (size_t)g * 32768;
#pragma unroll
    for (int e = 0; e < 16; ++e) {
        int u = e * 2048 + tid * 8;
        int row = u >> 7, c0 = u & 127;
        f16x8 v = *(const f16x8*)(src + u);
        f16* dst = L + row * 132 + c0;
        *(f16x4*)dst = lo4(v);
        *(f16x4*)(dst + 4) = hi4(v);
    }
    __syncthreads();
    const int j2 = tid & 15, bu = tid >> 4;
#pragma unroll 4
    for (int k = 0; k < 128; ++k) {
        int unit = bu + k * 16;        // 0..2047 -> (c, i2)
        int c = unit & 127, i2 = unit >> 7;
        float a = ab[c], bb = ab[128 + c];
        float v = fmaxf(a * (float)L[(i2 * 16 + j2) * 132 + c] + bb, 0.f);
        out[(((size_t)b * 128 + c) * 256 + i1 * 16 + i2) * 256 + j1 * 16 + j2] = v;
    }
}

// =====================================================================================
extern "C" void kernel_launch(void* const* d_in, const int* in_sizes, int n_in, void* d_out,
                              int out_size, void* d_ws, size_t ws_size, hipStream_t stream) {
    (void)in_sizes; (void)n_in; (void)out_size; (void)ws_size;
    const float* x = (const float*)d_in[0];
    const float* w1x = (const float*)d_in[1];
    const float* b1x = (const float*)d_in[2];
    const float* w1y = (const float*)d_in[3];
    const float* b1y = (const float*)d_in[4];
    const float* w1o = (const float*)d_in[5];
    const float* b1o = (const float*)d_in[6];
    const float* g1 = (const float*)d_in[7];
    const float* be1 = (const float*)d_in[8];
    const float* w2x = (const float*)d_in[9];
    const float* b2x = (const float*)d_in[10];
    const float* w2y = (const float*)d_in[11];
    const float* b2y = (const float*)d_in[12];
    const float* w2o = (const float*)d_in[13];
    const float* b2o = (const float*)d_in[14];
    const float* g2 = (const float*)d_in[15];
    const float* be2 = (const float*)d_in[16];

    // d_out doubles as scratch: [0,64MiB) Xall f16, [64MiB,128MiB) U1 f16 (both dead
    // before final_kernel rewrites d_out as fp32).
    f16* Xall = (f16*)d_out;
    f16* U1 = (f16*)((char*)d_out + 67108864);
    f16* U2 = (f16*)d_ws;
    f16* Wbf = (f16*)((char*)d_ws + 67108864);
    float* gstats = (float*)((char*)d_ws + 67108864 + 131072);  // [2][256]
    float* bnab = gstats + 512;                                 // [2][256]

    hipMemsetAsync(gstats, 0, 2048, stream);
    wconv_kernel<<<256, 256, 0, stream>>>(w1x, w1y, w1o, w2x, w2y, w2o, Wbf);
    repack_kernel<<<1024, 512, 0, stream>>>(x, Xall);

    att_kernel<1><<<1024, 512, 0, stream>>>(Xall, Wbf, Wbf + 8192, Wbf + 16384, b1x, b1y, b1o,
                                            (const float*)nullptr, U1, gstats, 32768, 128);
    bnfix_kernel<<<1, 128, 0, stream>>>(gstats, g1, be1, bnab);
    att_kernel<2><<<1024, 512, 0, stream>>>(U1, Wbf + 32768, Wbf + 40960, Wbf + 49152, b2x, b2y,
                                            b2o, bnab, U2, gstats + 256, 128, 32768);
    bnfix_kernel<<<1, 128, 0, stream>>>(gstats + 256, g2, be2, bnab + 256);
    final_kernel<<<1024, 256, 0, stream>>>(U2, bnab + 256, (float*)d_out);
}